// Round 2
// baseline (1553.104 us; speedup 1.0000x reference)
//
#include <hip/hip_runtime.h>
#include <stdint.h>

#define NROWS 16384
#define DDIM  5000
#define KP    5120       // padded K for gemm1 (160 k-steps of 32)
#define NB    192        // 3*L fused inner dim
#define NP    5184       // padded N for gemm2 (27 * 192)
#define DEC_SCALE 0.0159f

typedef __attribute__((ext_vector_type(8))) short  short8;
typedef __attribute__((ext_vector_type(4))) float  f32x4;
typedef __attribute__((ext_vector_type(4))) int    i32x4;

static __device__ __forceinline__ uint32_t fbits(float x){ union{float f;uint32_t u;}c; c.f=x; return c.u; }
static __device__ __forceinline__ float bitsf(uint32_t u){ union{float f;uint32_t u;}c; c.u=u; return c.f; }

// Split two f32 into packed bf16 hi (trunc) and bf16 lo (trunc of residual).
// x = hi + lo with |err| ~ 2^-16 |x|  -> hh + lh + hl MFMA products ~= fp32.
#define SPLIT2(xa, xb, H, L) {                                          \
    uint32_t ua = fbits(xa), ub = fbits(xb);                            \
    uint32_t ha = ua & 0xFFFF0000u, hb2 = ub & 0xFFFF0000u;             \
    (H) = (int)((ua >> 16) | hb2);                                      \
    (L) = (int)((fbits((xa) - bitsf(ha)) >> 16) |                       \
                (fbits((xb) - bitsf(hb2)) & 0xFFFF0000u)); }

// ---------------- prep kernels ----------------

__global__ void prep_wcat(const float* __restrict__ Wb, const float* __restrict__ Web,
                          const float* __restrict__ Wec,
                          unsigned short* __restrict__ Wh, unsigned short* __restrict__ Wl) {
    int total = NB * KP;
    for (int idx = blockIdx.x * blockDim.x + threadIdx.x; idx < total;
         idx += gridDim.x * blockDim.x) {
        int j = idx / KP, d = idx - j * KP;
        float v = 0.f;
        if (d < DDIM) {
            const float* src = (j < 64) ? Wb + (size_t)j * DDIM
                             : (j < 128) ? Web + (size_t)(j - 64) * DDIM
                             : Wec + (size_t)(j - 128) * DDIM;
            v = src[d];
        }
        uint32_t u = fbits(v);
        uint32_t h = u & 0xFFFF0000u;
        Wh[idx] = (unsigned short)(u >> 16);
        Wl[idx] = (unsigned short)(fbits(v - bitsf(h)) >> 16);
    }
}

__global__ void prep_bout(const float* __restrict__ Wb, const float* __restrict__ Wdb,
                          const float* __restrict__ Wdc,
                          unsigned short* __restrict__ Bh, unsigned short* __restrict__ Bl) {
    int total = NP * NB;
    for (int idx = blockIdx.x * blockDim.x + threadIdx.x; idx < total;
         idx += gridDim.x * blockDim.x) {
        int d = idx / NB, j = idx - d * NB;
        float v = 0.f;
        if (d < DDIM) {
            if (j < 64)       v = Wb[(size_t)j * DDIM + d];
            else if (j < 128) v = Wdb[(size_t)d * 64 + (j - 64)];
            else              v = Wdc[(size_t)d * 64 + (j - 128)];
        }
        uint32_t u = fbits(v);
        uint32_t h = u & 0xFFFF0000u;
        Bh[idx] = (unsigned short)(u >> 16);
        Bl[idx] = (unsigned short)(fbits(v - bitsf(h)) >> 16);
    }
}

// Transpose heads to [ctx][l][m] so the per-l broadcast read is coalesced over m.
__global__ void prep_heads(const float* __restrict__ Whb, const float* __restrict__ Whc,
                           float* __restrict__ Tb, float* __restrict__ Tc) {
    int total = 24 * 4096 + 10 * 4096;
    for (int idx = blockIdx.x * blockDim.x + threadIdx.x; idx < total;
         idx += gridDim.x * blockDim.x) {
        if (idx < 24 * 4096) {
            int ctx = idx >> 12, rem = idx & 4095, l = rem >> 6, m = rem & 63;
            Tb[idx] = Whb[(ctx << 12) + (m << 6) + l];
        } else {
            int i2 = idx - 24 * 4096;
            int ctx = i2 >> 12, rem = i2 & 4095, l = rem >> 6, m = rem & 63;
            Tc[i2] = Whc[(ctx << 12) + (m << 6) + l];
        }
    }
}

// ---------------- GEMM1: Hpart[kw][B][192] = expr * Wcat^T (split-bf16) ----------------
// grid = 256 blocks (BM=64), block = 1024 = 16 waves = 4 m-subtiles x 4 K-quarters.
// Each wave: one 16-row m-frag x 12 n-frags, K-quarter of 40 k-steps. No LDS, no barriers.

__global__ __launch_bounds__(1024) void gemm1(const float* __restrict__ expr,
                                              const unsigned short* __restrict__ Wh,
                                              const unsigned short* __restrict__ Wl,
                                              float* __restrict__ Hp) {
    const int lane = threadIdx.x & 63;
    const int wid  = threadIdx.x >> 6;
    const int kw   = wid & 3;          // K-quarter
    const int mw   = wid >> 2;         // m-subtile
    const int row  = blockIdx.x * 64 + mw * 16 + (lane & 15);
    const int kq   = lane >> 4;        // 0..3 -> k offset within 32

    f32x4 acc[12];
#pragma unroll
    for (int i = 0; i < 12; ++i) acc[i] = (f32x4)0.0f;

    const float* arow = expr + (size_t)row * DDIM;
    const int kbase = kw * (KP / 4);

    for (int s = 0; s < (KP / 4) / 32; ++s) {
        const int kk = kbase + s * 32 + kq * 8;
        short8 ah, al;
        if (kk < DDIM) {   // 5000 % 8 == 0, so the 8-elem group is entirely valid
            const float4* pa = reinterpret_cast<const float4*>(arow + kk);
            float4 x0 = pa[0], x1 = pa[1];
            i32x4 hv, lv;
            SPLIT2(x0.x, x0.y, hv[0], lv[0]);
            SPLIT2(x0.z, x0.w, hv[1], lv[1]);
            SPLIT2(x1.x, x1.y, hv[2], lv[2]);
            SPLIT2(x1.z, x1.w, hv[3], lv[3]);
            ah = __builtin_bit_cast(short8, hv);
            al = __builtin_bit_cast(short8, lv);
        } else {
            ah = (short8)0; al = (short8)0;
        }
#pragma unroll
        for (int nf = 0; nf < 12; ++nf) {
            const int j = nf * 16 + (lane & 15);
            const short8 bh = *reinterpret_cast<const short8*>(Wh + (size_t)j * KP + kk);
            const short8 bl = *reinterpret_cast<const short8*>(Wl + (size_t)j * KP + kk);
            acc[nf] = __builtin_amdgcn_mfma_f32_16x16x32_bf16(ah, bh, acc[nf], 0, 0, 0);
            acc[nf] = __builtin_amdgcn_mfma_f32_16x16x32_bf16(al, bh, acc[nf], 0, 0, 0);
            acc[nf] = __builtin_amdgcn_mfma_f32_16x16x32_bf16(ah, bl, acc[nf], 0, 0, 0);
        }
    }

    // D mapping: col = lane&15, row = (lane>>4)*4 + i
    const int orow0 = blockIdx.x * 64 + mw * 16 + (lane >> 4) * 4;
    const int ocol  = lane & 15;
    float* hp = Hp + (size_t)kw * ((size_t)NROWS * NB);
#pragma unroll
    for (int nf = 0; nf < 12; ++nf)
#pragma unroll
        for (int i = 0; i < 4; ++i)
            hp[(size_t)(orow0 + i) * NB + nf * 16 + ocol] = acc[nf][i];
}

// ---------------- heads: sum Hpart, apply per-row head matvecs, emit split G ----------------
// One wave per row. lane = output index m.

__global__ __launch_bounds__(256) void heads_k(const float* __restrict__ Hp,
                                               const int* __restrict__ srcb, const int* __restrict__ tgtb,
                                               const int* __restrict__ srcc, const int* __restrict__ tgtc,
                                               const float* __restrict__ Tb, const float* __restrict__ Tc,
                                               unsigned short* __restrict__ Gh, unsigned short* __restrict__ Gl) {
    const int lane = threadIdx.x & 63;
    const int wid  = threadIdx.x >> 6;
    const int b = blockIdx.x * 4 + wid;
    const size_t stride = (size_t)NROWS * NB;
    const float* h0 = Hp + (size_t)b * NB;

    float hb = h0[lane]       + h0[stride + lane]       + h0[2*stride + lane]       + h0[3*stride + lane];
    float sb = h0[64 + lane]  + h0[stride + 64 + lane]  + h0[2*stride + 64 + lane]  + h0[3*stride + 64 + lane];
    float sc = h0[128 + lane] + h0[stride + 128 + lane] + h0[2*stride + 128 + lane] + h0[3*stride + 128 + lane];

    const int csb = srcb[b], ctb = tgtb[b], csc = srcc[b], ctc = tgtc[b];

    // batch branch: hf = W[src]^T-gathered matvec, dec = same with tgt
    const float* Wsb = Tb + ((size_t)csb << 12);
    float hf = 0.f;
#pragma unroll 16
    for (int l = 0; l < 64; ++l) hf += __shfl(sb, l) * Wsb[(l << 6) + lane];
    const float* Wtb = Tb + ((size_t)ctb << 12);
    float db = 0.f;
#pragma unroll 16
    for (int l = 0; l < 64; ++l) db += __shfl(hf, l) * Wtb[(l << 6) + lane];

    // cell branch
    const float* Wsc = Tc + ((size_t)csc << 12);
    float hc = 0.f;
#pragma unroll 16
    for (int l = 0; l < 64; ++l) hc += __shfl(sc, l) * Wsc[(l << 6) + lane];
    const float* Wtc = Tc + ((size_t)ctc << 12);
    float dc = 0.f;
#pragma unroll 16
    for (int l = 0; l < 64; ++l) dc += __shfl(hc, l) * Wtc[(l << 6) + lane];

    db *= DEC_SCALE;
    dc *= DEC_SCALE;

    // write split G row: [h_base | scale*dec_b | scale*dec_c]
    const size_t gbase = (size_t)b * NB;
    float vals[3] = {hb, db, dc};
#pragma unroll
    for (int p = 0; p < 3; ++p) {
        uint32_t u = fbits(vals[p]);
        uint32_t h = u & 0xFFFF0000u;
        Gh[gbase + p * 64 + lane] = (unsigned short)(u >> 16);
        Gl[gbase + p * 64 + lane] = (unsigned short)(fbits(vals[p] - bitsf(h)) >> 16);
    }
}

// ---------------- GEMM2: out[B][5000] = G * Wout (split-bf16), K = 192 ----------------
// grid = (27, 256), block = 1024 = 16 waves = 4 m-subtiles x 4 n-subtiles.
// Each wave: 16 rows x 3 n-frags (48 cols), full K (6 k-steps). acc = 12 VGPR.

__global__ __launch_bounds__(1024) void gemm2(const unsigned short* __restrict__ Gh,
                                              const unsigned short* __restrict__ Gl,
                                              const unsigned short* __restrict__ Bh,
                                              const unsigned short* __restrict__ Bl,
                                              float* __restrict__ out) {
    const int lane = threadIdx.x & 63;
    const int wid  = threadIdx.x >> 6;
    const int nw   = wid & 3;
    const int mw   = wid >> 2;
    const int row  = blockIdx.y * 64 + mw * 16 + (lane & 15);
    const int col0 = blockIdx.x * NB + nw * 48;
    const int kq   = lane >> 4;

    f32x4 acc[3];
#pragma unroll
    for (int i = 0; i < 3; ++i) acc[i] = (f32x4)0.0f;

    const unsigned short* ga = Gh + (size_t)row * NB;
    const unsigned short* gb = Gl + (size_t)row * NB;

#pragma unroll
    for (int s = 0; s < 6; ++s) {
        const int kk = s * 32 + kq * 8;
        const short8 ah = *reinterpret_cast<const short8*>(ga + kk);
        const short8 al = *reinterpret_cast<const short8*>(gb + kk);
#pragma unroll
        for (int nf = 0; nf < 3; ++nf) {
            const int n = col0 + nf * 16 + (lane & 15);
            const short8 bh = *reinterpret_cast<const short8*>(Bh + (size_t)n * NB + kk);
            const short8 bl = *reinterpret_cast<const short8*>(Bl + (size_t)n * NB + kk);
            acc[nf] = __builtin_amdgcn_mfma_f32_16x16x32_bf16(ah, bh, acc[nf], 0, 0, 0);
            acc[nf] = __builtin_amdgcn_mfma_f32_16x16x32_bf16(al, bh, acc[nf], 0, 0, 0);
            acc[nf] = __builtin_amdgcn_mfma_f32_16x16x32_bf16(ah, bl, acc[nf], 0, 0, 0);
        }
    }

    const int orow0 = blockIdx.y * 64 + mw * 16 + kq * 4;
    const int ocolb = col0 + (lane & 15);
#pragma unroll
    for (int nf = 0; nf < 3; ++nf) {
        const int c = ocolb + nf * 16;
        if (c < DDIM) {
#pragma unroll
            for (int i = 0; i < 4; ++i)
                out[(size_t)(orow0 + i) * DDIM + c] = acc[nf][i];
        }
    }
}

// ---------------- launch ----------------

extern "C" void kernel_launch(void* const* d_in, const int* in_sizes, int n_in,
                              void* d_out, int out_size, void* d_ws, size_t ws_size,
                              hipStream_t stream) {
    const float* expr  = (const float*)d_in[0];
    const int* src_b   = (const int*)d_in[1];
    const int* tgt_b   = (const int*)d_in[2];
    const int* src_c   = (const int*)d_in[3];
    const int* tgt_c   = (const int*)d_in[4];
    const float* Wbase = (const float*)d_in[5];
    const float* Wencb = (const float*)d_in[6];
    const float* Wdecb = (const float*)d_in[7];
    const float* Whdb  = (const float*)d_in[8];
    const float* Wencc = (const float*)d_in[9];
    const float* Wdecc = (const float*)d_in[10];
    const float* Whdc  = (const float*)d_in[11];
    float* out = (float*)d_out;

    // workspace carve (all 16B aligned)
    char* ws = (char*)d_ws;
    unsigned short* Wch = (unsigned short*)ws;                         // NB*KP
    unsigned short* Wcl = Wch + (size_t)NB * KP;                       // NB*KP
    unsigned short* Bh  = Wcl + (size_t)NB * KP;                       // NP*NB
    unsigned short* Bl  = Bh  + (size_t)NP * NB;                       // NP*NB
    float* Tb = (float*)(Bl + (size_t)NP * NB);                        // 24*4096
    float* Tc = Tb + 24 * 4096;                                        // 10*4096
    float* Hp = Tc + 10 * 4096;                                        // 4*NROWS*NB
    unsigned short* Gh = (unsigned short*)(Hp + (size_t)4 * NROWS * NB);
    unsigned short* Gl = Gh + (size_t)NROWS * NB;

    prep_wcat<<<2048, 256, 0, stream>>>(Wbase, Wencb, Wencc, Wch, Wcl);
    prep_bout<<<2048, 256, 0, stream>>>(Wbase, Wdecb, Wdecc, Bh, Bl);
    prep_heads<<<544, 256, 0, stream>>>(Whdb, Whdc, Tb, Tc);
    gemm1<<<256, 1024, 0, stream>>>(expr, Wch, Wcl, Hp);
    heads_k<<<4096, 256, 0, stream>>>(Hp, src_b, tgt_b, src_c, tgt_c, Tb, Tc, Gh, Gl);
    gemm2<<<dim3(27, 256), 1024, 0, stream>>>(Gh, Gl, Bh, Bl, out);
}

// Round 4
// 991.228 us; speedup vs baseline: 1.5668x; 1.5668x over previous
//
#include <hip/hip_runtime.h>
#include <stdint.h>

#define NROWS 16384
#define DDIM  5000
#define NB    192        // 3*64 fused inner dim
#define NF1   12         // 16-col frags in gemm1 N (192/16)
#define NS1   160        // 32-k steps in gemm1 K (5120/32)
#define NF2T  324        // 16-col frags in gemm2 N (5184/16)
#define NS2   6          // 32-k steps in gemm2 K (192/32)
#define RF_N  1024       // 16-row frags over B (16384/16)
#define DEC_SCALE 0.0159f

typedef __attribute__((ext_vector_type(8))) short  short8;
typedef __attribute__((ext_vector_type(4))) float  f32x4;
typedef __attribute__((ext_vector_type(4))) int    i32x4;

static __device__ __forceinline__ uint32_t fbits(float x){ union{float f;uint32_t u;}c; c.f=x; return c.u; }
static __device__ __forceinline__ float bitsf(uint32_t u){ union{float f;uint32_t u;}c; c.u=u; return c.f; }

// Split two f32 into packed bf16 hi (trunc) + bf16 lo (trunc of residual).
#define SPLIT2(xa, xb, H, L) {                                          \
    uint32_t ua = fbits(xa), ub = fbits(xb);                            \
    uint32_t ha = ua & 0xFFFF0000u, hb2 = ub & 0xFFFF0000u;             \
    (H) = (int)((ua >> 16) | hb2);                                      \
    (L) = (int)((fbits((xa) - bitsf(ha)) >> 16) |                       \
                (fbits((xb) - bitsf(hb2)) & 0xFFFF0000u)); }

// ---------------- prep: pack Wcat^T (gemm1 B) into fragment order ----------------
// slot = (nf*NS1 + s)*64 + lane, lane = kq*16 + n16. Contents (16 shorts = 32B):
//   hi[j] = bf16h(Wcat[nf*16+n16][s*32+kq*8+j]), lo[j] = bf16l(...)
__global__ void prep_wp1(const float* __restrict__ Wb, const float* __restrict__ Web,
                         const float* __restrict__ Wec, unsigned short* __restrict__ Wp) {
    int slot = blockIdx.x * blockDim.x + threadIdx.x;
    if (slot >= NF1 * NS1 * 64) return;
    int lane = slot & 63, s = (slot >> 6) % NS1, nf = slot / (64 * NS1);
    int n16 = lane & 15, kq = lane >> 4;
    int n = nf * 16 + n16;
    int k0 = s * 32 + kq * 8;
    const float* src = (n < 64) ? Wb + (size_t)n * DDIM
                     : (n < 128) ? Web + (size_t)(n - 64) * DDIM
                     : Wec + (size_t)(n - 128) * DDIM;
    short8 hv, lv;
#pragma unroll
    for (int j = 0; j < 8; ++j) {
        float v = (k0 + j < DDIM) ? src[k0 + j] : 0.f;
        uint32_t u = fbits(v), hb = u & 0xFFFF0000u;
        hv[j] = (short)(u >> 16);
        lv[j] = (short)(fbits(v - bitsf(hb)) >> 16);
    }
    short8* dst = (short8*)(Wp + (size_t)slot * 16);
    dst[0] = hv; dst[1] = lv;
}

// ---------------- prep: pack Wout (gemm2 B) into fragment order ----------------
// B2[k][d]: k<64 -> Wb[k][d]; 64<=k<128 -> Wdb[d][k-64]; else Wdc[d][k-128]
__global__ void prep_wp2(const float* __restrict__ Wb, const float* __restrict__ Wdb,
                         const float* __restrict__ Wdc, unsigned short* __restrict__ Wp) {
    int slot = blockIdx.x * blockDim.x + threadIdx.x;
    if (slot >= NF2T * NS2 * 64) return;
    int lane = slot & 63, s = (slot >> 6) % NS2, fn = slot / (64 * NS2);
    int n16 = lane & 15, kq = lane >> 4;
    int n = fn * 16 + n16;
    int k0 = s * 32 + kq * 8;
    short8 hv, lv;
#pragma unroll
    for (int j = 0; j < 8; ++j) {
        int k = k0 + j;
        float v = 0.f;
        if (n < DDIM) {
            if (k < 64)       v = Wb[(size_t)k * DDIM + n];
            else if (k < 128) v = Wdb[(size_t)n * 64 + (k - 64)];
            else              v = Wdc[(size_t)n * 64 + (k - 128)];
        }
        uint32_t u = fbits(v), hb = u & 0xFFFF0000u;
        hv[j] = (short)(u >> 16);
        lv[j] = (short)(fbits(v - bitsf(hb)) >> 16);
    }
    short8* dst = (short8*)(Wp + (size_t)slot * 16);
    dst[0] = hv; dst[1] = lv;
}

// Transpose heads to [ctx][l][m] so per-l broadcast reads are coalesced over m.
__global__ void prep_heads(const float* __restrict__ Whb, const float* __restrict__ Whc,
                           float* __restrict__ Tb, float* __restrict__ Tc) {
    int total = 24 * 4096 + 10 * 4096;
    for (int idx = blockIdx.x * blockDim.x + threadIdx.x; idx < total;
         idx += gridDim.x * blockDim.x) {
        if (idx < 24 * 4096) {
            int ctx = idx >> 12, rem = idx & 4095, l = rem >> 6, m = rem & 63;
            Tb[idx] = Whb[(ctx << 12) + (m << 6) + l];
        } else {
            int i2 = idx - 24 * 4096;
            int ctx = i2 >> 12, rem = i2 & 4095, l = rem >> 6, m = rem & 63;
            Tc[i2] = Whc[(ctx << 12) + (m << 6) + l];
        }
    }
}

// ---------------- GEMM1: Hp[kw][B][192] = expr * Wcat^T (split-bf16) ----------------
// 256 blocks x 1024 thr = 16 waves = 4 mw x 4 kw. Wave: 16 rows x 12 nf, K-quarter.
// B loads fully coalesced from packed Wp1.
__global__ __launch_bounds__(1024) void gemm1(const float* __restrict__ expr,
                                              const unsigned short* __restrict__ Wp,
                                              float* __restrict__ Hp) {
    const int lane = threadIdx.x & 63;
    const int wid  = threadIdx.x >> 6;
    const int kw   = wid & 3;
    const int mw   = wid >> 2;
    const int row  = blockIdx.x * 64 + mw * 16 + (lane & 15);
    const int kq   = lane >> 4;

    f32x4 acc[NF1];
#pragma unroll
    for (int i = 0; i < NF1; ++i) acc[i] = (f32x4)0.0f;

    const float* arow = expr + (size_t)row * DDIM;

    for (int s = kw * 40; s < kw * 40 + 40; ++s) {
        const int kk = s * 32 + kq * 8;
        short8 ah, al;
        if (kk < DDIM) {
            const float4* pa = reinterpret_cast<const float4*>(arow + kk);
            float4 x0 = pa[0], x1 = pa[1];
            i32x4 hv, lv;
            SPLIT2(x0.x, x0.y, hv[0], lv[0]);
            SPLIT2(x0.z, x0.w, hv[1], lv[1]);
            SPLIT2(x1.x, x1.y, hv[2], lv[2]);
            SPLIT2(x1.z, x1.w, hv[3], lv[3]);
            ah = __builtin_bit_cast(short8, hv);
            al = __builtin_bit_cast(short8, lv);
        } else {
            ah = (short8)0; al = (short8)0;
        }
        const unsigned short* bp = Wp + ((size_t)s * 64 + lane) * 16;
#pragma unroll
        for (int nf = 0; nf < NF1; ++nf) {
            const short8 bh = *(const short8*)(bp);
            const short8 bl = *(const short8*)(bp + 8);
            bp += (size_t)NS1 * 64 * 16;
            acc[nf] = __builtin_amdgcn_mfma_f32_16x16x32_bf16(ah, bh, acc[nf], 0, 0, 0);
            acc[nf] = __builtin_amdgcn_mfma_f32_16x16x32_bf16(al, bh, acc[nf], 0, 0, 0);
            acc[nf] = __builtin_amdgcn_mfma_f32_16x16x32_bf16(ah, bl, acc[nf], 0, 0, 0);
        }
    }

    const int orow0 = blockIdx.x * 64 + mw * 16 + kq * 4;
    float* hp = Hp + (size_t)kw * ((size_t)NROWS * NB) + (size_t)orow0 * NB + (lane & 15);
#pragma unroll
    for (int nf = 0; nf < NF1; ++nf)
#pragma unroll
        for (int i = 0; i < 4; ++i)
            hp[(size_t)i * NB + nf * 16] = acc[nf][i];
}

// ---------------- heads: sum Hp partials, head matvecs, emit packed split Gp ----------------
// 1024 blocks x 1024 thr: wave w handles row b = blk*16 + w; then LDS repack to
// fragment order: Gp slot = (rf*NS2 + s)*64 + lane, lane = kq*16 + r16.
__global__ __launch_bounds__(1024) void heads_k(const float* __restrict__ Hp,
                                                const int* __restrict__ srcb, const int* __restrict__ tgtb,
                                                const int* __restrict__ srcc, const int* __restrict__ tgtc,
                                                const float* __restrict__ Tb, const float* __restrict__ Tc,
                                                unsigned short* __restrict__ Gp) {
    __shared__ float Gs[16][193];
    const int lane = threadIdx.x & 63;
    const int w    = threadIdx.x >> 6;       // row within block, 0..15
    const int b    = blockIdx.x * 16 + w;
    const size_t stride = (size_t)NROWS * NB;
    const float* h0 = Hp + (size_t)b * NB;

    float hb = h0[lane]       + h0[stride + lane]       + h0[2*stride + lane]       + h0[3*stride + lane];
    float sb = h0[64 + lane]  + h0[stride + 64 + lane]  + h0[2*stride + 64 + lane]  + h0[3*stride + 64 + lane];
    float sc = h0[128 + lane] + h0[stride + 128 + lane] + h0[2*stride + 128 + lane] + h0[3*stride + 128 + lane];

    const int csb = srcb[b], ctb = tgtb[b], csc = srcc[b], ctc = tgtc[b];

    const float* Wsb = Tb + ((size_t)csb << 12);
    float hf = 0.f;
#pragma unroll 16
    for (int l = 0; l < 64; ++l) hf += __shfl(sb, l) * Wsb[(l << 6) + lane];
    const float* Wtb = Tb + ((size_t)ctb << 12);
    float db = 0.f;
#pragma unroll 16
    for (int l = 0; l < 64; ++l) db += __shfl(hf, l) * Wtb[(l << 6) + lane];

    const float* Wsc = Tc + ((size_t)csc << 12);
    float hc = 0.f;
#pragma unroll 16
    for (int l = 0; l < 64; ++l) hc += __shfl(sc, l) * Wsc[(l << 6) + lane];
    const float* Wtc = Tc + ((size_t)ctc << 12);
    float dc = 0.f;
#pragma unroll 16
    for (int l = 0; l < 64; ++l) dc += __shfl(hc, l) * Wtc[(l << 6) + lane];

    Gs[w][lane]       = hb;
    Gs[w][64 + lane]  = db * DEC_SCALE;
    Gs[w][128 + lane] = dc * DEC_SCALE;
    __syncthreads();

    const int t = threadIdx.x;
    if (t < NS2 * 64) {                       // 384 pack slots
        const int lane2 = t & 63, s = t >> 6;
        const int r16 = lane2 & 15, kq = lane2 >> 4;
        short8 hv, lv;
#pragma unroll
        for (int j = 0; j < 8; ++j) {
            float v = Gs[r16][s * 32 + kq * 8 + j];
            uint32_t u = fbits(v), hbb = u & 0xFFFF0000u;
            hv[j] = (short)(u >> 16);
            lv[j] = (short)(fbits(v - bitsf(hbb)) >> 16);
        }
        short8* dst = (short8*)(Gp + (((size_t)blockIdx.x * NS2 + s) * 64 + lane2) * 16);
        dst[0] = hv; dst[1] = lv;
    }
}

// ---------------- GEMM2: out[B][5000] = G * Wout (split-bf16), K = 192 ----------------
// grid (27, 128) x 512 thr = 8 waves. Wave: 16 rows x 12 nf (192 cols), full K.
__global__ __launch_bounds__(512) void gemm2(const unsigned short* __restrict__ Gp,
                                             const unsigned short* __restrict__ Wp,
                                             float* __restrict__ out) {
    const int lane = threadIdx.x & 63;
    const int wid  = threadIdx.x >> 6;       // 0..7
    const int rf   = blockIdx.y * 8 + wid;   // row-frag 0..1023
    const int fn0  = blockIdx.x * 12;

    f32x4 acc[12];
#pragma unroll
    for (int i = 0; i < 12; ++i) acc[i] = (f32x4)0.0f;

#pragma unroll
    for (int s = 0; s < NS2; ++s) {
        const unsigned short* ap = Gp + (((size_t)rf * NS2 + s) * 64 + lane) * 16;
        const short8 ah = *(const short8*)(ap);
        const short8 al = *(const short8*)(ap + 8);
        const unsigned short* bp = Wp + (((size_t)fn0 * NS2 + s) * 64 + lane) * 16;
#pragma unroll
        for (int nf = 0; nf < 12; ++nf) {
            const short8 bh = *(const short8*)(bp);
            const short8 bl = *(const short8*)(bp + 8);
            bp += (size_t)NS2 * 64 * 16;
            acc[nf] = __builtin_amdgcn_mfma_f32_16x16x32_bf16(ah, bh, acc[nf], 0, 0, 0);
            acc[nf] = __builtin_amdgcn_mfma_f32_16x16x32_bf16(al, bh, acc[nf], 0, 0, 0);
            acc[nf] = __builtin_amdgcn_mfma_f32_16x16x32_bf16(ah, bl, acc[nf], 0, 0, 0);
        }
    }

    const int orow0 = blockIdx.y * 128 + wid * 16 + (lane >> 4) * 4;
    const int c0    = blockIdx.x * NB + (lane & 15);
#pragma unroll
    for (int nf = 0; nf < 12; ++nf) {
        const int c = c0 + nf * 16;
        if (c < DDIM) {
#pragma unroll
            for (int i = 0; i < 4; ++i)
                out[(size_t)(orow0 + i) * DDIM + c] = acc[nf][i];
        }
    }
}

// ---------------- launch ----------------

extern "C" void kernel_launch(void* const* d_in, const int* in_sizes, int n_in,
                              void* d_out, int out_size, void* d_ws, size_t ws_size,
                              hipStream_t stream) {
    const float* expr  = (const float*)d_in[0];
    const int* src_b   = (const int*)d_in[1];
    const int* tgt_b   = (const int*)d_in[2];
    const int* src_c   = (const int*)d_in[3];
    const int* tgt_c   = (const int*)d_in[4];
    const float* Wbase = (const float*)d_in[5];
    const float* Wencb = (const float*)d_in[6];
    const float* Wdecb = (const float*)d_in[7];
    const float* Whdb  = (const float*)d_in[8];
    const float* Wencc = (const float*)d_in[9];
    const float* Wdecc = (const float*)d_in[10];
    const float* Whdc  = (const float*)d_in[11];
    float* out = (float*)d_out;

    // workspace carve (all 16B aligned)
    char* ws = (char*)d_ws;
    unsigned short* Wp1 = (unsigned short*)ws;                         // NF1*NS1*64*16 shorts
    unsigned short* Wp2 = Wp1 + (size_t)NF1 * NS1 * 64 * 16;           // NF2T*NS2*64*16
    float* Tb = (float*)(Wp2 + (size_t)NF2T * NS2 * 64 * 16);          // 24*4096
    float* Tc = Tb + 24 * 4096;                                        // 10*4096
    float* Hp = Tc + 10 * 4096;                                        // 4*NROWS*NB
    unsigned short* Gp = (unsigned short*)(Hp + (size_t)4 * NROWS * NB); // RF_N*NS2*64*16

    prep_wp1<<<(NF1 * NS1 * 64 + 255) / 256, 256, 0, stream>>>(Wbase, Wencb, Wencc, Wp1);
    prep_wp2<<<(NF2T * NS2 * 64 + 255) / 256, 256, 0, stream>>>(Wbase, Wdecb, Wdecc, Wp2);
    prep_heads<<<544, 256, 0, stream>>>(Whdb, Whdc, Tb, Tc);
    gemm1<<<256, 1024, 0, stream>>>(expr, Wp1, Hp);
    heads_k<<<RF_N, 1024, 0, stream>>>(Hp, src_b, tgt_b, src_c, tgt_c, Tb, Tc, Gp);
    gemm2<<<dim3(27, 128), 512, 0, stream>>>(Gp, Wp2, out);
}

// Round 5
// 741.177 us; speedup vs baseline: 2.0955x; 1.3374x over previous
//
#include <hip/hip_runtime.h>
#include <stdint.h>

#define NROWS 16384
#define DDIM  5000
#define NB    192        // 3*64 fused inner dim
#define NF1   12         // 16-col frags per 192
#define NS1   160        // 32-k steps in gemm1 K (5120/32, zero-padded past 5000)
#define NPAN  27         // 192-col panels in gemm2 N (27*192 = 5184 >= 5000)
#define NS2   6          // 32-k steps in gemm2 K (192/32)
#define DEC_SCALE 0.0159f

typedef __attribute__((ext_vector_type(8))) short  short8;
typedef __attribute__((ext_vector_type(4))) float  f32x4;
typedef __attribute__((ext_vector_type(4))) int    i32x4;

static __device__ __forceinline__ uint32_t fbits(float x){ union{float f;uint32_t u;}c; c.f=x; return c.u; }
static __device__ __forceinline__ float bitsf(uint32_t u){ union{float f;uint32_t u;}c; c.u=u; return c.f; }
// round-to-nearest-even-ish bf16 (unbiased, for B operands)
static __device__ __forceinline__ unsigned short bf16rn(float x){
    uint32_t u = fbits(x);
    return (unsigned short)((u + 0x7FFFu + ((u >> 16) & 1u)) >> 16);
}
// A-side split: hi = trunc-bf16(x), lo = trunc-bf16(x - hi); x ~= hi + lo (30-bit exact)
#define SPLIT2(xa, xb, H, L) {                                          \
    uint32_t ua = fbits(xa), ub = fbits(xb);                            \
    uint32_t ha = ua & 0xFFFF0000u, hb2 = ub & 0xFFFF0000u;             \
    (H) = (int)((ua >> 16) | hb2);                                      \
    (L) = (int)((fbits((xa) - bitsf(ha)) >> 16) |                       \
                (fbits((xb) - bitsf(hb2)) & 0xFFFF0000u)); }

#define MFMA(a, b, c) __builtin_amdgcn_mfma_f32_16x16x32_bf16((a), (b), (c), 0, 0, 0)
// async global->LDS, 16B per lane; LDS dest is wave-uniform base + lane*16
#define GLL16(g, l) __builtin_amdgcn_global_load_lds(                   \
    (const __attribute__((address_space(1))) void*)(g),                 \
    (__attribute__((address_space(3))) void*)(l), 16, 0, 0)

// ---------------- prep: Wcat^T (gemm1 B, bf16-RN) in step-major fragment order ------
// short index = ((s*NF1 + nf)*64 + lane)*8 ; lane = kq*16 + n16
// content[j] = bf16rn(Wcat[nf*16+n16][s*32+kq*8+j]) (0 past DDIM)
__global__ void prep_wp1(const float* __restrict__ Wb, const float* __restrict__ Web,
                         const float* __restrict__ Wec, unsigned short* __restrict__ Wp) {
    int slot = blockIdx.x * blockDim.x + threadIdx.x;
    if (slot >= NS1 * NF1 * 64) return;
    int lane = slot & 63, nf = (slot >> 6) % NF1, s = slot / (64 * NF1);
    int n = nf * 16 + (lane & 15);
    int k0 = s * 32 + (lane >> 4) * 8;
    const float* src = (n < 64) ? Wb + (size_t)n * DDIM
                     : (n < 128) ? Web + (size_t)(n - 64) * DDIM
                     : Wec + (size_t)(n - 128) * DDIM;
    short8 hv;
#pragma unroll
    for (int j = 0; j < 8; ++j) {
        float v = (k0 + j < DDIM) ? src[k0 + j] : 0.f;
        hv[j] = (short)bf16rn(v);
    }
    *(short8*)(Wp + (size_t)slot * 8) = hv;
}

// ---------------- prep: Wout (gemm2 B, bf16-RN), panel-major fragment order --------
// short index = (((panel*NS2 + s)*NF1 + nf)*64 + lane)*8
// B2[k][d]: k<64 -> Wb[k][d]; 64<=k<128 -> Wdb[d][k-64]; else Wdc[d][k-128]
__global__ void prep_wp2(const float* __restrict__ Wb, const float* __restrict__ Wdb,
                         const float* __restrict__ Wdc, unsigned short* __restrict__ Wp) {
    int slot = blockIdx.x * blockDim.x + threadIdx.x;
    if (slot >= NPAN * NS2 * NF1 * 64) return;
    int lane = slot & 63;
    int tmp  = slot >> 6;
    int nf = tmp % NF1; tmp /= NF1;
    int s  = tmp % NS2;
    int panel = tmp / NS2;
    int n = panel * NB + nf * 16 + (lane & 15);
    int k0 = s * 32 + (lane >> 4) * 8;
    short8 hv;
#pragma unroll
    for (int j = 0; j < 8; ++j) {
        int k = k0 + j;
        float v = 0.f;
        if (n < DDIM) {
            if (k < 64)       v = Wb[(size_t)k * DDIM + n];
            else if (k < 128) v = Wdb[(size_t)n * 64 + (k - 64)];
            else              v = Wdc[(size_t)n * 64 + (k - 128)];
        }
        hv[j] = (short)bf16rn(v);
    }
    *(short8*)(Wp + (size_t)slot * 8) = hv;
}

// Transpose heads to [ctx][l][m] so per-l broadcast reads are coalesced over m.
__global__ void prep_heads(const float* __restrict__ Whb, const float* __restrict__ Whc,
                           float* __restrict__ Tb, float* __restrict__ Tc) {
    int total = 24 * 4096 + 10 * 4096;
    for (int idx = blockIdx.x * blockDim.x + threadIdx.x; idx < total;
         idx += gridDim.x * blockDim.x) {
        if (idx < 24 * 4096) {
            int ctx = idx >> 12, rem = idx & 4095, l = rem >> 6, m = rem & 63;
            Tb[idx] = Whb[(ctx << 12) + (m << 6) + l];
        } else {
            int i2 = idx - 24 * 4096;
            int ctx = i2 >> 12, rem = i2 & 4095, l = rem >> 6, m = rem & 63;
            Tc[i2] = Whc[(ctx << 12) + (m << 6) + l];
        }
    }
}

// ---------------- GEMM1: H[B][192] = expr * Wcat^T (A split-bf16 x2, B bf16-RN) ----
// grid 512 x 512 thr = 8 waves = 2 mw x 4 nw; BM=32; full K per wave.
// B double-buffered in LDS via global_load_lds; A prefetched 1 step ahead.
__global__ __launch_bounds__(512) void gemm1(const float* __restrict__ expr,
                                             const unsigned short* __restrict__ Wp,
                                             float* __restrict__ Hp) {
    __shared__ unsigned short Bs[2][NF1 * 64 * 8];   // 12 KB per buffer
    const int t = threadIdx.x;
    const int lane = t & 63, wid = t >> 6;
    const int mw = wid >> 2, nw = wid & 3;
    const int r16 = lane & 15, kq = lane >> 4;
    const int row = blockIdx.x * 32 + mw * 16 + r16;
    const float* arow = expr + (size_t)row * DDIM;

    f32x4 acc0 = (f32x4)0.f, acc1 = (f32x4)0.f, acc2 = (f32x4)0.f;

    // prologue: stage s=0, load A(0)
    {
        const char* src = (const char*)Wp;
        char* dst = (char*)&Bs[0][0];
        GLL16(src + t * 16, dst + t * 16);
        if (t < 256) GLL16(src + 8192 + t * 16, dst + 8192 + t * 16);
    }
    float4 x0, x1;
    {
        const float4* pa = (const float4*)(arow + kq * 8);
        x0 = pa[0]; x1 = pa[1];
    }
    __syncthreads();   // drains vmcnt -> buf0 staged

    int cur = 0;
    for (int s = 0; s < NS1; ++s) {
        // stage next step's B into the other buffer (in-flight across MFMA phase)
        if (s + 1 < NS1) {
            const char* src = (const char*)Wp + (size_t)(s + 1) * (NF1 * 64 * 16);
            char* dst = (char*)&Bs[cur ^ 1][0];
            GLL16(src + t * 16, dst + t * 16);
            if (t < 256) GLL16(src + 8192 + t * 16, dst + 8192 + t * 16);
        }
        // prefetch next A
        float4 y0 = make_float4(0.f, 0.f, 0.f, 0.f), y1 = y0;
        const int kk2 = (s + 1) * 32 + kq * 8;
        if (s + 1 < NS1 && kk2 < DDIM) {
            const float4* pa = (const float4*)(arow + kk2);
            y0 = pa[0]; y1 = pa[1];
        }
        // split current A (exact hi+lo)
        i32x4 hv, lv;
        SPLIT2(x0.x, x0.y, hv[0], lv[0]);
        SPLIT2(x0.z, x0.w, hv[1], lv[1]);
        SPLIT2(x1.x, x1.y, hv[2], lv[2]);
        SPLIT2(x1.z, x1.w, hv[3], lv[3]);
        const short8 ah = __builtin_bit_cast(short8, hv);
        const short8 al = __builtin_bit_cast(short8, lv);
        // B fragments from LDS (lane-contiguous 16B -> conflict-free ds_read_b128)
        const unsigned short* bs = &Bs[cur][0] + (nw * 3) * 512 + lane * 8;
        const short8 b0 = *(const short8*)(bs);
        const short8 b1 = *(const short8*)(bs + 512);
        const short8 b2 = *(const short8*)(bs + 1024);
        acc0 = MFMA(ah, b0, acc0); acc0 = MFMA(al, b0, acc0);
        acc1 = MFMA(ah, b1, acc1); acc1 = MFMA(al, b1, acc1);
        acc2 = MFMA(ah, b2, acc2); acc2 = MFMA(al, b2, acc2);
        __syncthreads();   // drains vmcnt (next-B staged, next-A in regs) + all ds_reads
        cur ^= 1; x0 = y0; x1 = y1;
    }

    // D mapping: col = lane&15, row = kq*4 + i
    const int orow = blockIdx.x * 32 + mw * 16 + kq * 4;
    float* hp = Hp + (size_t)orow * NB + nw * 48 + r16;
#pragma unroll
    for (int i = 0; i < 4; ++i) {
        hp[(size_t)i * NB +  0] = acc0[i];
        hp[(size_t)i * NB + 16] = acc1[i];
        hp[(size_t)i * NB + 32] = acc2[i];
    }
}

// ---------------- heads: head matvecs on H, emit packed split Gp -------------------
// grid 1024 x 1024 thr: wave w -> row b = blk*16 + w; LDS repack to fragment order
// Gp short idx = ((rf*NS2 + s)*64 + lane)*16 (hi8|lo8), lane = kq*16 + r16.
__global__ __launch_bounds__(1024) void heads_k(const float* __restrict__ H,
                                                const int* __restrict__ srcb, const int* __restrict__ tgtb,
                                                const int* __restrict__ srcc, const int* __restrict__ tgtc,
                                                const float* __restrict__ Tb, const float* __restrict__ Tc,
                                                unsigned short* __restrict__ Gp) {
    __shared__ float Gs[16][193];
    const int lane = threadIdx.x & 63;
    const int w    = threadIdx.x >> 6;
    const int b    = blockIdx.x * 16 + w;
    const float* h0 = H + (size_t)b * NB;

    float hb = h0[lane];
    float sb = h0[64 + lane];
    float sc = h0[128 + lane];

    const int csb = srcb[b], ctb = tgtb[b], csc = srcc[b], ctc = tgtc[b];

    const float* Wsb = Tb + ((size_t)csb << 12);
    float hf = 0.f;
#pragma unroll 16
    for (int l = 0; l < 64; ++l) hf += __shfl(sb, l) * Wsb[(l << 6) + lane];
    const float* Wtb = Tb + ((size_t)ctb << 12);
    float db = 0.f;
#pragma unroll 16
    for (int l = 0; l < 64; ++l) db += __shfl(hf, l) * Wtb[(l << 6) + lane];

    const float* Wsc = Tc + ((size_t)csc << 12);
    float hc = 0.f;
#pragma unroll 16
    for (int l = 0; l < 64; ++l) hc += __shfl(sc, l) * Wsc[(l << 6) + lane];
    const float* Wtc = Tc + ((size_t)ctc << 12);
    float dc = 0.f;
#pragma unroll 16
    for (int l = 0; l < 64; ++l) dc += __shfl(hc, l) * Wtc[(l << 6) + lane];

    Gs[w][lane]       = hb;
    Gs[w][64 + lane]  = db * DEC_SCALE;
    Gs[w][128 + lane] = dc * DEC_SCALE;
    __syncthreads();

    const int t = threadIdx.x;
    if (t < NS2 * 64) {                       // 384 pack slots
        const int lane2 = t & 63, s = t >> 6;
        const int r16 = lane2 & 15, kq = lane2 >> 4;
        short8 hv, lv;
#pragma unroll
        for (int j = 0; j < 8; ++j) {
            float v = Gs[r16][s * 32 + kq * 8 + j];
            uint32_t u = fbits(v), hbb = u & 0xFFFF0000u;
            hv[j] = (short)(u >> 16);
            lv[j] = (short)(fbits(v - bitsf(hbb)) >> 16);
        }
        short8* dst = (short8*)(Gp + (((size_t)blockIdx.x * NS2 + s) * 64 + lane2) * 16);
        dst[0] = hv; dst[1] = lv;
    }
}

// ---------------- GEMM2: out[B][5000] = G * Wout (G split x2, B bf16-RN) -----------
// grid (27, 64) x 512 thr = 8 waves; block: 256 rows x 192-col panel; B panel (74KB)
// staged once in LDS; each wave: 32 rows (2 rfrags) x 12 nf, full K.
__global__ __launch_bounds__(512) void gemm2(const unsigned short* __restrict__ Gp,
                                             const unsigned short* __restrict__ Wp,
                                             float* __restrict__ out) {
    __shared__ unsigned short Bs[NS2 * NF1 * 64 * 8];   // 73728 B
    const int t = threadIdx.x, lane = t & 63, wid = t >> 6;
    const int r16 = lane & 15, kq = lane >> 4;
    const int panel = blockIdx.x;
    const int rowbase = blockIdx.y * 256 + wid * 32;
    const int rf0 = rowbase >> 4;

    {
        const char* src = (const char*)Wp + (size_t)panel * (NS2 * NF1 * 64 * 16);
        char* dst = (char*)&Bs[0];
#pragma unroll
        for (int r = 0; r < 9; ++r)
            GLL16(src + r * 8192 + t * 16, dst + r * 8192 + t * 16);
    }

    f32x4 acc0[12], acc1[12];
#pragma unroll
    for (int i = 0; i < 12; ++i) { acc0[i] = (f32x4)0.f; acc1[i] = (f32x4)0.f; }
    __syncthreads();   // panel staged

#pragma unroll
    for (int s = 0; s < NS2; ++s) {
        const unsigned short* g0 = Gp + (((size_t)rf0 * NS2 + s) * 64 + lane) * 16;
        const unsigned short* g1 = g0 + (size_t)NS2 * 64 * 16;
        const short8 ah0 = *(const short8*)(g0);
        const short8 al0 = *(const short8*)(g0 + 8);
        const short8 ah1 = *(const short8*)(g1);
        const short8 al1 = *(const short8*)(g1 + 8);
        const unsigned short* bs = &Bs[0] + s * (NF1 * 512) + lane * 8;
#pragma unroll
        for (int nf = 0; nf < 12; ++nf) {
            const short8 b = *(const short8*)(bs + nf * 512);
            acc0[nf] = MFMA(ah0, b, acc0[nf]); acc0[nf] = MFMA(al0, b, acc0[nf]);
            acc1[nf] = MFMA(ah1, b, acc1[nf]); acc1[nf] = MFMA(al1, b, acc1[nf]);
        }
    }

    const int c0 = panel * NB + r16;
#pragma unroll
    for (int nf = 0; nf < 12; ++nf) {
        const int c = c0 + nf * 16;
        if (c < DDIM) {
            const int orow = rowbase + kq * 4;
#pragma unroll
            for (int i = 0; i < 4; ++i)
                out[(size_t)(orow + i) * DDIM + c] = acc0[nf][i];
#pragma unroll
            for (int i = 0; i < 4; ++i)
                out[(size_t)(orow + 16 + i) * DDIM + c] = acc1[nf][i];
        }
    }
}

// ---------------- launch ----------------

extern "C" void kernel_launch(void* const* d_in, const int* in_sizes, int n_in,
                              void* d_out, int out_size, void* d_ws, size_t ws_size,
                              hipStream_t stream) {
    const float* expr  = (const float*)d_in[0];
    const int* src_b   = (const int*)d_in[1];
    const int* tgt_b   = (const int*)d_in[2];
    const int* src_c   = (const int*)d_in[3];
    const int* tgt_c   = (const int*)d_in[4];
    const float* Wbase = (const float*)d_in[5];
    const float* Wencb = (const float*)d_in[6];
    const float* Wdecb = (const float*)d_in[7];
    const float* Whdb  = (const float*)d_in[8];
    const float* Wencc = (const float*)d_in[9];
    const float* Wdecc = (const float*)d_in[10];
    const float* Whdc  = (const float*)d_in[11];
    float* out = (float*)d_out;

    // workspace carve (16B aligned)
    char* ws = (char*)d_ws;
    unsigned short* Wp1 = (unsigned short*)ws;                           // 160*12*512 shorts
    unsigned short* Wp2 = Wp1 + (size_t)NS1 * NF1 * 512;                 // 27*6*12*512 shorts
    float* Tb = (float*)(Wp2 + (size_t)NPAN * NS2 * NF1 * 512);          // 24*4096
    float* Tc = Tb + 24 * 4096;                                          // 10*4096
    float* Hp = Tc + 10 * 4096;                                          // NROWS*NB
    unsigned short* Gp = (unsigned short*)(Hp + (size_t)NROWS * NB);     // 1024*6*64*16 shorts

    prep_wp1<<<(NS1 * NF1 * 64 + 255) / 256, 256, 0, stream>>>(Wbase, Wencb, Wencc, Wp1);
    prep_wp2<<<(NPAN * NS2 * NF1 * 64 + 255) / 256, 256, 0, stream>>>(Wbase, Wdecb, Wdecc, Wp2);
    prep_heads<<<544, 256, 0, stream>>>(Whdb, Whdc, Tb, Tc);
    gemm1<<<512, 512, 0, stream>>>(expr, Wp1, Hp);
    heads_k<<<1024, 1024, 0, stream>>>(Hp, src_b, tgt_b, src_c, tgt_c, Tb, Tc, Gp);
    gemm2<<<dim3(NPAN, 64), 512, 0, stream>>>(Gp, Wp2, out);
}